// Round 1
// baseline (170.228 us; speedup 1.0000x reference)
//
#include <hip/hip_runtime.h>
#include <hip/hip_cooperative_groups.h>

namespace cg = cooperative_groups;

// Problem constants (reference: B,N,D,OUT = 4,512,128,128)
#define B_ 4
#define N_ 512
#define D_ 128
#define O_ 128

#define R1 8     // rows per block (phase 1 & 2 use the SAME row mapping)
#define TI 8
#define JS 8
#define JB 16    // j-batch width

// ---------------------------------------------------------------------------
// Fused EdgeConv: one cooperative kernel, 256 blocks x 1024 threads (1/CU).
//
// Phase 1 (= old gemm_pq): q = x@W2 -> global workspace; phat = x@(W1-W2)+b
// stays in ONE register per thread: the phase-1 reduce thread (rr,oo) and the
// phase-2 epilogue thread (i,oo) address the identical output element
// (row = bid*8 + (tid>>7), o = tid&127), so phat never round-trips global.
//
// grid.sync(): q written by all 256 blocks must be visible cross-XCD.
// __threadfence() = agent-scope release before the handshake.
//
// Phase 2 (= old maskmax): out[b,i,o] = relu(phat + max_j(adj*1024 + q) - 1024).
// Mask trick unchanged: adj in {0,1}; masked-in candidates dominate by >1000.
// ---------------------------------------------------------------------------
__global__ __launch_bounds__(1024, 4)
void fused_edgeconv(const float* __restrict__ x, const float* __restrict__ adj,
                    const float* __restrict__ W, const float* __restrict__ bias,
                    float* __restrict__ q, float* __restrict__ out) {
    const int tid = threadIdx.x;
    const int bid = blockIdx.x;

    // Phase 1 uses both buffers (redq/redp); phase 2 reuses bufA as `part`.
    // Inner dim padded to 9: lane stride 9 floats -> only the free 2-way alias.
    __shared__ float bufA[R1][O_][9];   // 36 KB
    __shared__ float bufB[R1][O_][9];   // 36 KB

    // ---------------- Phase 1: q -> global, phat -> register ----------------
    float phat_reg;
    {
        const int o  = tid & (O_ - 1);
        const int kq = __builtin_amdgcn_readfirstlane(tid >> 7);  // 0..7, uniform
        const int row0 = bid * R1;
        const float* __restrict__ xb = x + (size_t)row0 * D_;

        float accp[R1], accq[R1];
#pragma unroll
        for (int r = 0; r < R1; ++r) { accp[r] = 0.0f; accq[r] = 0.0f; }

        const int k0 = kq * (D_ / 8);               // 16 k's per group
#pragma unroll 4
        for (int k = k0; k < k0 + D_ / 8; ++k) {
            const float w1 = W[(size_t)k * O_ + o];          // coalesced, L2-hot
            const float w2 = W[(size_t)(k + D_) * O_ + o];
            const float wd = w1 - w2;
#pragma unroll
            for (int r = 0; r < R1; ++r) {
                const float xv = xb[(size_t)r * D_ + k];     // uniform -> s_load
                accp[r] = fmaf(xv, wd, accp[r]);
                accq[r] = fmaf(xv, w2, accq[r]);
            }
        }

#pragma unroll
        for (int r = 0; r < R1; ++r) {
            bufA[r][o][kq] = accq[r];
            bufB[r][o][kq] = accp[r];
        }
        __syncthreads();

        {   // exactly R1*O_ = 1024 (r,o) pairs for 1024 threads
            const int rr = tid >> 7;
            const int oo = tid & (O_ - 1);
            const float sq = ((bufA[rr][oo][0] + bufA[rr][oo][1]) +
                              (bufA[rr][oo][2] + bufA[rr][oo][3])) +
                             ((bufA[rr][oo][4] + bufA[rr][oo][5]) +
                              (bufA[rr][oo][6] + bufA[rr][oo][7]));
            const float sp = ((bufB[rr][oo][0] + bufB[rr][oo][1]) +
                              (bufB[rr][oo][2] + bufB[rr][oo][3])) +
                             ((bufB[rr][oo][4] + bufB[rr][oo][5]) +
                              (bufB[rr][oo][6] + bufB[rr][oo][7]));
            q[(size_t)(row0 + rr) * O_ + oo] = sq;
            phat_reg = sp + bias[oo];               // lives across grid.sync
        }
    }

    __threadfence();            // release q stores to device scope (cross-XCD)
    cg::this_grid().sync();     // all 2048 q-rows now visible everywhere

    // ---------------- Phase 2: out = relu(phat + maskmax(q)) ----------------
    {
        const int o  = tid & (O_ - 1);
        const int jq = __builtin_amdgcn_readfirstlane(tid >> 7);   // 0..7
        const int b  = bid >> 6;                 // N/TI = 64 tiles per batch
        const int i0 = (bid & 63) * TI;          // == (bid*R1) % N_  (same rows as phase 1)

        const float* __restrict__ qb   = q + (size_t)b * N_ * O_ + o;
        const float* __restrict__ arow = adj + ((size_t)b * N_ + i0) * N_;

        float m[TI];
#pragma unroll
        for (int i = 0; i < TI; ++i) m[i] = -1e30f;

        const int j0   = jq * (N_ / JS);        // 64 j's per group
        const int jend = j0 + (N_ / JS);

        float qv[JB], qn[JB];
#pragma unroll
        for (int u = 0; u < JB; ++u)
            qv[u] = qb[(size_t)(j0 + u) * O_];  // prologue: 16 in flight

        for (int j = j0; j < jend; j += JB) {   // 4 iterations
            const int jn = (j + JB < jend) ? (j + JB) : j0;
#pragma unroll
            for (int u = 0; u < JB; ++u)
                qn[u] = qb[(size_t)(jn + u) * O_];

#pragma unroll
            for (int i = 0; i < TI; ++i) {
                const float* __restrict__ ar = arow + (size_t)i * N_ + j; // uniform -> s_load
                float c[JB];
#pragma unroll
                for (int u = 0; u < JB; ++u)
                    c[u] = fmaf(ar[u], 1024.0f, qv[u]);
                float mi = m[i];
#pragma unroll
                for (int u = 0; u < JB; u += 4) {   // pairs -> v_max3 folding
                    mi = fmaxf(mi, fmaxf(c[u],     c[u + 1]));
                    mi = fmaxf(mi, fmaxf(c[u + 2], c[u + 3]));
                }
                m[i] = mi;
            }

#pragma unroll
            for (int u = 0; u < JB; ++u) qv[u] = qn[u];  // rotate
        }

        __syncthreads();                        // safety before reusing bufA
#pragma unroll
        for (int i = 0; i < TI; ++i) bufA[i][o][jq] = m[i];
        __syncthreads();

        {   // exactly TI*O_ = 1024 (i,o) pairs for 1024 threads
            const int i  = tid >> 7;
            const int oo = tid & (O_ - 1);
            float mm = -1e30f;
#pragma unroll
            for (int p = 0; p < JS; ++p) mm = fmaxf(mm, bufA[i][oo][p]);
            const float v = phat_reg + mm - 1024.0f;   // phat from phase-1 register
            out[((size_t)b * N_ + i0 + i) * O_ + oo] = v > 0.0f ? v : 0.0f;
        }
    }
}

// ---------------------------------------------------------------------------
extern "C" void kernel_launch(void* const* d_in, const int* in_sizes, int n_in,
                              void* d_out, int out_size, void* d_ws, size_t ws_size,
                              hipStream_t stream) {
    const float* x    = (const float*)d_in[0];   // (B,N,D)
    const float* adj  = (const float*)d_in[1];   // (B,N,N)
    const float* W    = (const float*)d_in[2];   // (2D, OUT)
    const float* bias = (const float*)d_in[3];   // (OUT,)
    float* out = (float*)d_out;                  // (B,N,OUT)

    float* q = (float*)d_ws;                     // B*N*O_ floats = 1 MB (only ws use)

    void* args[] = { (void*)&x, (void*)&adj, (void*)&W, (void*)&bias,
                     (void*)&q, (void*)&out };
    hipLaunchCooperativeKernel((void*)fused_edgeconv,
                               dim3((B_ * N_) / R1), dim3(1024),
                               args, 0, stream);
}

// Round 2
// 74.280 us; speedup vs baseline: 2.2917x; 2.2917x over previous
//
#include <hip/hip_runtime.h>

// Problem constants (reference: B,N,D,OUT = 4,512,128,128)
#define B_ 4
#define N_ 512
#define D_ 128
#define O_ 128

// ---------------------------------------------------------------------------
// K1: q = x @ W2 ; phat = x @ (W1 - W2) + bias
// 512 blocks x 1024 threads (2 blocks/CU -> 32 waves/CU for latency hiding;
// round-1 counters showed VALUBusy 7.5% / Occupancy 44% at 1 block/CU).
// o = tid&127 (coalesced W loads), kq = tid>>7 splits K=128 8 ways.
// x values are wave-uniform -> scalar loads. Dual LDS buffers (36 KB)
// -> ONE barrier for both reduces.
// ---------------------------------------------------------------------------
#define R1 4

__global__ __launch_bounds__(1024, 8)   // cap VGPR <= 64 -> 32 waves/CU
void gemm_pq_kernel(const float* __restrict__ x, const float* __restrict__ W,
                    const float* __restrict__ bias, float* __restrict__ q,
                    float* __restrict__ phat) {
    const int tid = threadIdx.x;
    const int o   = tid & (O_ - 1);
    const int kq  = __builtin_amdgcn_readfirstlane(tid >> 7);  // 0..7, uniform
    const int row0 = blockIdx.x * R1;

    const float* __restrict__ xb = x + (size_t)row0 * D_;

    float accp[R1], accq[R1];
#pragma unroll
    for (int r = 0; r < R1; ++r) { accp[r] = 0.0f; accq[r] = 0.0f; }

    const int k0 = kq * (D_ / 8);               // 16 k's per group
#pragma unroll 4
    for (int k = k0; k < k0 + D_ / 8; ++k) {
        const float w1 = W[(size_t)k * O_ + o];          // coalesced, L2-hot
        const float w2 = W[(size_t)(k + D_) * O_ + o];
        const float wd = w1 - w2;
#pragma unroll
        for (int r = 0; r < R1; ++r) {
            const float xv = xb[(size_t)r * D_ + k];     // uniform -> s_load
            accp[r] = fmaf(xv, wd, accp[r]);
            accq[r] = fmaf(xv, w2, accq[r]);
        }
    }

    // pad inner dim to 9: lane stride 9 floats -> only the free 2-way alias
    __shared__ float redq[R1][O_][9];                    // 18 KB
    __shared__ float redp[R1][O_][9];                    // 18 KB

#pragma unroll
    for (int r = 0; r < R1; ++r) {
        redq[r][o][kq] = accq[r];
        redp[r][o][kq] = accp[r];
    }
    __syncthreads();                            // the ONLY barrier

    if (tid < R1 * O_) {                        // 512 (r,o) pairs
        const int rr = tid >> 7;
        const int oo = tid & (O_ - 1);
        const float sq = ((redq[rr][oo][0] + redq[rr][oo][1]) +
                          (redq[rr][oo][2] + redq[rr][oo][3])) +
                         ((redq[rr][oo][4] + redq[rr][oo][5]) +
                          (redq[rr][oo][6] + redq[rr][oo][7]));
        const float sp = ((redp[rr][oo][0] + redp[rr][oo][1]) +
                          (redp[rr][oo][2] + redp[rr][oo][3])) +
                         ((redp[rr][oo][4] + redp[rr][oo][5]) +
                          (redp[rr][oo][6] + redp[rr][oo][7]));
        const size_t idx = (size_t)(row0 + rr) * O_ + oo;
        q[idx]    = sq;
        phat[idx] = sp + bias[oo];
    }
}

// ---------------------------------------------------------------------------
// K2: out[b,i,o] = relu(phat[b,i,o] + max_{j:adj[b,i,j]!=0} q[b,j,o])
// Mask trick: adj in {0,1}; cand = fma(adj, 1024, qv); masked-in candidates
// dominate by >1000 (|q| <= ~5). Epilogue subtracts 1024. Empty neighbor
// row -> phat + maxq - 1024 < 0 -> relu -> 0, matching the reference.
//
// 512 blocks x 1024 threads (2 blocks/CU, 32 waves/CU): o = tid&127,
// jq = tid>>7 (wave-uniform -> adj loads ride the scalar pipe). TI=4
// i-rows/block; j split 8 ways (64 each), processed in batches of 16 with
// prefetch-next-16: 16-32 q-loads in flight covers cold cross-XCD L3
// latency (~400-900 cyc).
// ---------------------------------------------------------------------------
#define TI 4
#define JS 8
#define JB 16     // j-batch width

__global__ __launch_bounds__(1024, 8)   // cap VGPR <= 64 -> 32 waves/CU
void maskmax_kernel(const float* __restrict__ q, const float* __restrict__ phat,
                    const float* __restrict__ adj, float* __restrict__ out) {
    const int tid = threadIdx.x;
    const int o   = tid & (O_ - 1);
    const int jq  = __builtin_amdgcn_readfirstlane(tid >> 7);   // 0..7
    const int b   = blockIdx.x >> 7;            // N/TI = 128 tiles per batch
    const int i0  = (blockIdx.x & 127) * TI;

    const float* __restrict__ qb   = q + (size_t)b * N_ * O_ + o;
    const float* __restrict__ arow = adj + ((size_t)b * N_ + i0) * N_;

    float m[TI];
#pragma unroll
    for (int i = 0; i < TI; ++i) m[i] = -1e30f;

    const int j0   = jq * (N_ / JS);            // 64 j's per group
    const int jend = j0 + (N_ / JS);

    float qv[JB], qn[JB];
#pragma unroll
    for (int u = 0; u < JB; ++u)
        qv[u] = qb[(size_t)(j0 + u) * O_];      // prologue: 16 in flight

    for (int j = j0; j < jend; j += JB) {       // 4 iterations
        // prefetch next batch (uniform select, no branch; wraps harmlessly)
        const int jn = (j + JB < jend) ? (j + JB) : j0;
#pragma unroll
        for (int u = 0; u < JB; ++u)
            qn[u] = qb[(size_t)(jn + u) * O_];

#pragma unroll
        for (int i = 0; i < TI; ++i) {
            const float* __restrict__ ar = arow + (size_t)i * N_ + j; // uniform -> s_load
            float c[JB];
#pragma unroll
            for (int u = 0; u < JB; ++u)
                c[u] = fmaf(ar[u], 1024.0f, qv[u]);
            float mi = m[i];
#pragma unroll
            for (int u = 0; u < JB; u += 4) {   // pairs -> v_max3 folding
                mi = fmaxf(mi, fmaxf(c[u],     c[u + 1]));
                mi = fmaxf(mi, fmaxf(c[u + 2], c[u + 3]));
            }
            m[i] = mi;
        }

#pragma unroll
        for (int u = 0; u < JB; ++u) qv[u] = qn[u];  // rotate
    }

    // combine the 8 j-groups; pad inner dim to 9 -> only the free 2-way alias
    __shared__ float part[TI][O_][JS + 1];      // 18 KB
#pragma unroll
    for (int i = 0; i < TI; ++i) part[i][o][jq] = m[i];
    __syncthreads();

    if (tid < TI * O_) {                        // 512 (i,o) pairs
        const int i  = tid >> 7;
        const int oo = tid & (O_ - 1);
        float mm = -1e30f;
#pragma unroll
        for (int p = 0; p < JS; ++p) mm = fmaxf(mm, part[i][oo][p]);
        const size_t idx = ((size_t)b * N_ + i0 + i) * O_ + oo;
        const float v = phat[idx] + mm - 1024.0f;
        out[idx] = v > 0.0f ? v : 0.0f;
    }
}

// ---------------------------------------------------------------------------
extern "C" void kernel_launch(void* const* d_in, const int* in_sizes, int n_in,
                              void* d_out, int out_size, void* d_ws, size_t ws_size,
                              hipStream_t stream) {
    const float* x    = (const float*)d_in[0];   // (B,N,D)
    const float* adj  = (const float*)d_in[1];   // (B,N,N)
    const float* W    = (const float*)d_in[2];   // (2D, OUT)
    const float* bias = (const float*)d_in[3];   // (OUT,)
    float* out = (float*)d_out;                  // (B,N,OUT)

    float* q    = (float*)d_ws;                        // B*N*O_ floats = 1 MB
    float* phat = q + (size_t)B_ * N_ * O_;            // 1 MB

    gemm_pq_kernel<<<(B_ * N_) / R1, 1024, 0, stream>>>(x, W, bias, q, phat);
    maskmax_kernel<<<B_ * (N_ / TI), 1024, 0, stream>>>(q, phat, adj, out);
}